// Round 4
// baseline (532.405 us; speedup 1.0000x reference)
//
#include <hip/hip_runtime.h>
#include <hip/hip_bf16.h>

#define BB 32
#define TT 1600
#define EE 1024
#define AA 512
#define CC 10
#define KW 201

typedef __attribute__((ext_vector_type(8))) short short8;
typedef __attribute__((ext_vector_type(4))) float f32x4;

__device__ __forceinline__ float sigm(float x) { return 1.f / (1.f + expf(-x)); }

// pack 2 floats -> 2 bf16 (RNE): v_cvt_pk_bf16_f32
__device__ __forceinline__ unsigned int cvt2(float a, float b) {
    float2 f2; f2.x = a; f2.y = b;
    __hip_bfloat162 h = __float22bfloat162_rn(f2);
    unsigned int r;
    __builtin_memcpy(&r, &h, 4);
    return r;
}

// async global->LDS 16 B/lane (global_load_lds_dwordx4); dest must be lane-linear
__device__ __forceinline__ void gl_lds16(const void* g, void* l) {
    __builtin_amdgcn_global_load_lds(
        (const __attribute__((address_space(1))) unsigned int*)g,
        (__attribute__((address_space(3))) unsigned int*)l, 16, 0, 0);
}

// ---------------- ws layout (float units) ----------------
#define AF_OFF   0        // att_feat 32*10 = 320
#define R_OFF    320      // r = h_new + dec_proj: 16384
#define E_OFF    16704    // e scores: 51200
#define WBF_OFF  67904    // W_enc bf16: 524288 shorts = 262144 floats

// ---------------- out layout (float units) ----------------
#define CTX_OFF 0
#define W_OFF   32768
#define H_OFF   83968
#define C_OFF   100352

// K1: bx<320: location conv; 320..831: W_enc f32->bf16; 832..863: zero ctx
__global__ void prep_kernel(const float* __restrict__ att_prev,
                            const float* __restrict__ conv_w,
                            const float* __restrict__ W_enc,
                            float* __restrict__ af,
                            unsigned short* __restrict__ Wbf,
                            float* __restrict__ out) {
    int bx = blockIdx.x, tid = threadIdx.x;
    if (bx >= 832) {   // zero ctx region (32768 floats = 8192 float4)
        int i = (bx - 832) * 256 + tid;
        reinterpret_cast<float4*>(out + CTX_OFF)[i] = (float4){0.f, 0.f, 0.f, 0.f};
        return;
    }
    if (bx >= 320) {   // W_enc cvt
        int i = (bx - 320) * 256 + tid;   // float4 unit, 131072 total
        float4 v = reinterpret_cast<const float4*>(W_enc)[i];
        uint2 p;
        p.x = cvt2(v.x, v.y);
        p.y = cvt2(v.z, v.w);
        reinterpret_cast<uint2*>(Wbf)[i] = p;
        return;
    }
    int b = bx / 10, c = bx % 10;
    __shared__ float xs[1808];
    __shared__ float wsm[KW];
    __shared__ float red[256];
    const float* xp = att_prev + b * TT;
    for (int i = tid; i < 1808; i += 256) {
        int g = i - 100;
        xs[i] = (g >= 0 && g < TT) ? xp[g] : 0.f;
    }
    if (tid < KW) wsm[tid] = conv_w[c * KW + tid];
    __syncthreads();
    float mx = 0.f;   // relu >= 0
    #pragma unroll 1
    for (int sweep = 0; sweep < 2; ++sweep) {
        int t0 = sweep * 1024 + tid * 4;
        if (t0 >= TT) break;
        float a0 = xs[t0], a1 = xs[t0 + 1], a2 = xs[t0 + 2], a3 = xs[t0 + 3];
        float s0 = 0.f, s1 = 0.f, s2 = 0.f, s3 = 0.f;
        #pragma unroll 4
        for (int k = 0; k < KW; ++k) {
            float w = wsm[k];
            s0 += w * a0; s1 += w * a1; s2 += w * a2; s3 += w * a3;
            a0 = a1; a1 = a2; a2 = a3;
            a3 = xs[t0 + k + 4];
        }
        mx = fmaxf(mx, fmaxf(fmaxf(s0, s1), fmaxf(s2, s3)));
    }
    red[tid] = mx; __syncthreads();
    for (int s = 128; s > 0; s >>= 1) {
        if (tid < s) red[tid] = fmaxf(red[tid], red[tid + s]);
        __syncthreads();
    }
    if (tid == 0) af[b * CC + c] = red[0];
}

// K2: gates + dec_proj + LSTM + r (unchanged from round 3, passed)
__global__ void gates_lstm_kernel(const float* __restrict__ af,
                                  const float* __restrict__ att_h,
                                  const float* __restrict__ dec_z,
                                  const float* __restrict__ att_c,
                                  const float* __restrict__ W_ih,
                                  const float* __restrict__ W_hh,
                                  const float* __restrict__ W_dec,
                                  float* __restrict__ out,
                                  float* __restrict__ r_ws) {
    __shared__ float gsm[8][32];
    __shared__ float dsm[8][32];
    int tid = threadIdx.x;
    int a0 = blockIdx.x * 2;
    int b = tid & 31;
    if (tid < 256) {
        int u = tid >> 5;
        int gate = u >> 1, ai = u & 1;
        int j = gate * 512 + a0 + ai;
        float s = 0.f;
        #pragma unroll
        for (int k = 0; k < 10; ++k) s += af[b * 10 + k] * W_ih[j * 10 + k];
        const float4* wr = reinterpret_cast<const float4*>(W_hh + (size_t)j * 512);
        const float4* hr = reinterpret_cast<const float4*>(att_h + b * 512);
        #pragma unroll 4
        for (int k = 0; k < 128; ++k) {
            float4 w = wr[k], h = hr[k];
            s += w.x * h.x + w.y * h.y + w.z * h.z + w.w * h.w;
        }
        gsm[u][b] = s;
    } else {
        int v = (tid - 256) >> 5;
        int ai = v & 1, q = v >> 1;
        int a = a0 + ai;
        const float4* wr = reinterpret_cast<const float4*>(W_dec + (size_t)a * 1024) + q * 64;
        const float4* zr = reinterpret_cast<const float4*>(dec_z + (size_t)b * 1024) + q * 64;
        float s = 0.f;
        #pragma unroll 4
        for (int k = 0; k < 64; ++k) {
            float4 w = wr[k], z = zr[k];
            s += w.x * z.x + w.y * z.y + w.z * z.z + w.w * z.w;
        }
        dsm[v][b] = s;
    }
    __syncthreads();
    if (tid < 64) {
        int ai = tid >> 5;
        int a = a0 + ai;
        float ig = gsm[ai][b], fg = gsm[2 + ai][b], gg = gsm[4 + ai][b], og = gsm[6 + ai][b];
        float cn = sigm(fg) * att_c[b * 512 + a] + sigm(ig) * tanhf(gg);
        float hn = sigm(og) * tanhf(cn);
        out[H_OFF + b * 512 + a] = hn;
        out[C_OFF + b * 512 + a] = cn;
        float dec = dsm[ai][b] + dsm[2 + ai][b] + dsm[4 + ai][b] + dsm[6 + ai][b];
        r_ws[b * 512 + a] = hn + dec;
    }
}

// K3: fused score GEMM. 800 blocks x 512 thr (8 waves). Tile 64M x 512N, BK=32.
// A (f32) read from HBM exactly once, staged raw via global_load_lds, converted
// to bf16 at fragment-read time (2x ds_read_b128 + 4 v_cvt_pk per frag).
// B = pre-converted bf16 W_enc, global_load_lds (L2-resident re-read).
// XOR-swizzled LDS slots: all b128 frag reads are 2-way (free).
// Wave tile 64x64 -> 16 MFMA per wave per barrier-pair; ~2 blocks/CU overlap.
__global__ void __launch_bounds__(512, 2)
score_gemm_kernel(const float* __restrict__ enc,
                  const unsigned short* __restrict__ Wbf,
                  const float* __restrict__ b_enc,
                  const float* __restrict__ r_ws,
                  const float* __restrict__ W_g,
                  float* __restrict__ e_ws) {
    __shared__ __align__(16) float As[512 * 4];     // 512 slots x 16B (64 rows x 32 k, f32)
    __shared__ __align__(16) short Bs[2048 * 8];    // 2048 slots x 16B (512 n x 32 k, bf16)
    __shared__ float e_part[8][64];

    int tid = threadIdx.x;
    int lane = tid & 63, wv = tid >> 6;
    int col = lane & 15, quad = lane >> 4;
    int m0 = blockIdx.x * 64;

    // ---- staging source pointers (slot -> global mapping, swizzle-inverse) ----
    // A: slot s=tid: row=s>>3, kgp=s&7, kg=kgp^(row&7); 16B = 4 floats
    {
    }
    int a_row = tid >> 3;
    int a_kg = (tid & 7) ^ (a_row & 7);
    const float* a_src = enc + (size_t)(m0 + a_row) * EE + a_kg * 4;
    // B: slots s=tid+512*j: n=s>>2, kgp=s&3, kg=kgp^((n>>1)&3); 16B = 8 bf16
    const unsigned short* b_src[4];
    #pragma unroll
    for (int j = 0; j < 4; ++j) {
        int s = tid + 512 * j;
        int n = s >> 2;
        int kg = (s & 3) ^ ((n >> 1) & 3);
        b_src[j] = Wbf + (size_t)n * EE + kg * 8;
    }

    f32x4 acc[4][4];
    #pragma unroll
    for (int mt = 0; mt < 4; ++mt)
        #pragma unroll
        for (int nt = 0; nt < 4; ++nt)
            acc[mt][nt] = (f32x4){0.f, 0.f, 0.f, 0.f};

    int aswz = col & 7;           // (row&7) for r = mt*16+col
    int bswz = (col >> 1) & 3;    // ((n>>1)&3) for n = wv*64+nt*16+col

    for (int k0 = 0; k0 < EE; k0 += 32) {
        __syncthreads();   // previous chunk fully consumed
        gl_lds16(a_src + k0, &As[tid * 4]);
        #pragma unroll
        for (int j = 0; j < 4; ++j)
            gl_lds16(b_src[j] + k0, &Bs[(tid + 512 * j) * 8]);
        __syncthreads();   // drain staging

        short8 a_frag[4];
        #pragma unroll
        for (int mt = 0; mt < 4; ++mt) {
            int s0 = (mt * 16 + col) * 8 + ((2 * quad) ^ aswz);
            float4 fa = *reinterpret_cast<const float4*>(&As[s0 * 4]);
            float4 fb = *reinterpret_cast<const float4*>(&As[(s0 ^ 1) * 4]);
            uint4 u;
            u.x = cvt2(fa.x, fa.y); u.y = cvt2(fa.z, fa.w);
            u.z = cvt2(fb.x, fb.y); u.w = cvt2(fb.z, fb.w);
            __builtin_memcpy(&a_frag[mt], &u, 16);
        }
        #pragma unroll
        for (int nt = 0; nt < 4; ++nt) {
            int slot = (wv * 64 + nt * 16 + col) * 4 + (quad ^ bswz);
            short8 bf = *reinterpret_cast<const short8*>(&Bs[slot * 8]);
            #pragma unroll
            for (int mt = 0; mt < 4; ++mt)
                acc[mt][nt] = __builtin_amdgcn_mfma_f32_16x16x32_bf16(
                    a_frag[mt], bf, acc[mt][nt], 0, 0, 0);
        }
    }

    // ---- epilogue: e[m] = sum_n wg[n]*tanh(acc + b_enc[n] + r[b][n]) ----
    int bb = blockIdx.x / 25;   // 64-row tiles never straddle batch rows
    float wg[4], bn[4], rr[4];
    #pragma unroll
    for (int nt = 0; nt < 4; ++nt) {
        int n = wv * 64 + nt * 16 + col;
        wg[nt] = W_g[n];
        bn[nt] = b_enc[n];
        rr[nt] = r_ws[bb * AA + n];
    }
    #pragma unroll
    for (int mt = 0; mt < 4; ++mt) {
        #pragma unroll
        for (int reg = 0; reg < 4; ++reg) {
            float p = 0.f;
            #pragma unroll
            for (int nt = 0; nt < 4; ++nt)
                p += wg[nt] * tanhf(acc[mt][nt][reg] + bn[nt] + rr[nt]);
            p += __shfl_xor(p, 1);
            p += __shfl_xor(p, 2);
            p += __shfl_xor(p, 4);
            p += __shfl_xor(p, 8);
            if (col == 0) e_part[wv][mt * 16 + quad * 4 + reg] = p;
        }
    }
    __syncthreads();
    if (tid < 64) {
        float s = 0.f;
        #pragma unroll
        for (int i = 0; i < 8; ++i) s += e_part[i][tid];
        e_ws[m0 + tid] = s;
    }
}

// K4: masked softmax over T, scaling 2.0 (b_g dropped: shift-invariant)
__global__ void softmax_kernel(const float* __restrict__ e_ws,
                               const int* __restrict__ lens,
                               float* __restrict__ w_out) {
    int b = blockIdx.x, tid = threadIdx.x;
    int len = lens[b];
    const float* e = e_ws + b * TT;
    __shared__ float red[256];
    float mx = -3.4e38f;
    for (int t = tid; t < len; t += 256) mx = fmaxf(mx, e[t]);
    red[tid] = mx; __syncthreads();
    for (int s = 128; s > 0; s >>= 1) {
        if (tid < s) red[tid] = fmaxf(red[tid], red[tid + s]);
        __syncthreads();
    }
    mx = red[0]; __syncthreads();
    float sum = 0.f;
    for (int t = tid; t < len; t += 256) sum += expf(2.f * (e[t] - mx));
    red[tid] = sum; __syncthreads();
    for (int s = 128; s > 0; s >>= 1) {
        if (tid < s) red[tid] += red[tid + s];
        __syncthreads();
    }
    float inv = 1.f / red[0];
    for (int t = tid; t < TT; t += 256)
        w_out[b * TT + t] = (t < len) ? expf(2.f * (e[t] - mx)) * inv : 0.f;
}

// K5: ctx[b,:] += sum_t w[b,t]*enc[b,t,:]; grid (32, 25), 64 t per block
__global__ void ctx_kernel(const float* __restrict__ enc,
                           const float* __restrict__ w,
                           float* __restrict__ ctx) {
    int b = blockIdx.x, seg = blockIdx.y;
    int t0 = seg * 64;
    const float* wrow = w + b * TT + t0;
    const float* base = enc + ((size_t)(b * TT + t0)) * EE + threadIdx.x * 4;
    float4 acc = {0.f, 0.f, 0.f, 0.f};
    #pragma unroll 1
    for (int i = 0; i < 64; i += 4) {
        float w0 = wrow[i], w1 = wrow[i + 1], w2 = wrow[i + 2], w3 = wrow[i + 3];
        float4 v0 = *reinterpret_cast<const float4*>(base + (size_t)(i + 0) * EE);
        float4 v1 = *reinterpret_cast<const float4*>(base + (size_t)(i + 1) * EE);
        float4 v2 = *reinterpret_cast<const float4*>(base + (size_t)(i + 2) * EE);
        float4 v3 = *reinterpret_cast<const float4*>(base + (size_t)(i + 3) * EE);
        acc.x += w0 * v0.x + w1 * v1.x + w2 * v2.x + w3 * v3.x;
        acc.y += w0 * v0.y + w1 * v1.y + w2 * v2.y + w3 * v3.y;
        acc.z += w0 * v0.z + w1 * v1.z + w2 * v2.z + w3 * v3.z;
        acc.w += w0 * v0.w + w1 * v1.w + w2 * v2.w + w3 * v3.w;
    }
    float* dst = ctx + b * EE + threadIdx.x * 4;
    atomicAdd(dst + 0, acc.x);
    atomicAdd(dst + 1, acc.y);
    atomicAdd(dst + 2, acc.z);
    atomicAdd(dst + 3, acc.w);
}

extern "C" void kernel_launch(void* const* d_in, const int* in_sizes, int n_in,
                              void* d_out, int out_size, void* d_ws, size_t ws_size,
                              hipStream_t stream) {
    const float* enc      = (const float*)d_in[0];
    const int*   lens     = (const int*)d_in[1];
    const float* dec_z    = (const float*)d_in[2];
    const float* att_prev = (const float*)d_in[3];
    const float* att_h    = (const float*)d_in[4];
    const float* att_c    = (const float*)d_in[5];
    const float* W_enc    = (const float*)d_in[6];
    const float* b_enc    = (const float*)d_in[7];
    const float* W_dec    = (const float*)d_in[8];
    const float* conv_w   = (const float*)d_in[9];
    const float* W_ih     = (const float*)d_in[10];
    const float* W_hh     = (const float*)d_in[11];
    const float* W_g      = (const float*)d_in[12];

    float* out = (float*)d_out;
    float* ws  = (float*)d_ws;
    float* af   = ws + AF_OFF;
    float* r_ws = ws + R_OFF;
    float* e_ws = ws + E_OFF;
    unsigned short* Wbf = (unsigned short*)(ws + WBF_OFF);

    prep_kernel<<<864, 256, 0, stream>>>(att_prev, conv_w, W_enc, af, Wbf, out);
    gates_lstm_kernel<<<256, 512, 0, stream>>>(af, att_h, dec_z, att_c,
                                               W_ih, W_hh, W_dec, out, r_ws);
    score_gemm_kernel<<<800, 512, 0, stream>>>(enc, Wbf, b_enc, r_ws, W_g, e_ws);
    softmax_kernel<<<BB, 256, 0, stream>>>(e_ws, lens, out + W_OFF);
    ctx_kernel<<<dim3(BB, 25), 256, 0, stream>>>(enc, out + W_OFF, out + CTX_OFF);
}